// Round 11
// baseline (366.401 us; speedup 1.0000x reference)
//
#include <hip/hip_runtime.h>

#define HH 512
#define WW 512
#define SS (HH * WW)          // elements per plane (2^18)
#define P16N (16 * SS)        // 16 planes (2^22)
#define PADW 576              // skewed LDS row: addr(j) = j + (j>>3)
#define DPW (2 * PADW)        // dual-half row: [s1 : 576 | s2 : 576]

constexpr float FINF = 3.402823466e38f;

__device__ __forceinline__ int swz(int j) { return j + (j >> 3); }

__device__ __forceinline__ float gray1(float r, float g, float b) {
    return 0.299f * r + 0.587f * g + 0.114f * b;
}

// inverse of small integer c in [R+1, 2R+1] without v_div (cmp+cndmask chain)
template <int R>
__device__ __forceinline__ float invsmall(int c) {
    float r = 1.f / (float)(2 * R + 1);
    #pragma unroll
    for (int v = R + 1; v < 2 * R + 1; ++v)
        if (c == v) r = 1.f / (float)v;      // compile-time constants
    return r;
}

// ---------------- grad (gray fused, both dirs, 4 px/thread) ----------------
__global__ __launch_bounds__(256) void grad_both(const float* __restrict__ rgb,
                                                 float* __restrict__ dst,
                                                 int gxp0, int gyp0, int dirsel) {
    int sp = blockIdx.x * 256 + threadIdx.x;
    int idx = sp << 2;                             // [0, P16N)
    int img = idx >> 18;
    int pix = idx & (SS - 1);
    int i = pix >> 9, j0 = pix & (WW - 1);
    const float* p0 = rgb + (size_t)img * 3 * SS + pix;

    float4 r = *(const float4*)p0;
    float4 g = *(const float4*)(p0 + SS);
    float4 b = *(const float4*)(p0 + 2 * SS);
    float4 gy4 = make_float4(gray1(r.x, g.x, b.x), gray1(r.y, g.y, b.y),
                             gray1(r.z, g.z, b.z), gray1(r.w, g.w, b.w));
    if (dirsel != 1) {
        float grs = 0.f;
        if (j0 + 4 < WW) grs = gray1(p0[4], p0[SS + 4], p0[2 * SS + 4]);
        float4 gx = make_float4(gy4.x - gy4.y, gy4.y - gy4.z, gy4.z - gy4.w, gy4.w - grs);
        *(float4*)(dst + (size_t)(gxp0 + img) * SS + pix) = gx;
    }
    if (dirsel != 0) {
        float4 gd = make_float4(0.f, 0.f, 0.f, 0.f);
        if (i < HH - 1) {
            float4 r2 = *(const float4*)(p0 + WW);
            float4 g2 = *(const float4*)(p0 + SS + WW);
            float4 b2 = *(const float4*)(p0 + 2 * SS + WW);
            gd = make_float4(gray1(r2.x, g2.x, b2.x), gray1(r2.y, g2.y, b2.y),
                             gray1(r2.z, g2.z, b2.z), gray1(r2.w, g2.w, b2.w));
        }
        float4 gy = make_float4(gy4.x - gd.x, gy4.y - gd.y, gy4.z - gd.z, gy4.w - gd.w);
        *(float4*)(dst + (size_t)(gyp0 + img) * SS + pix) = gy;
    }
}

// ---------------- dual max+min pool (column-first, skewed LDS) ----------------
// SINGLE ring buffer rb[W]; exact wrap-counted validity mask (compile-time
// except i0). Phase-split over ONE LDS buffer (36864 B -> 4 blocks/CU):
// vertical max -> LDS, min -> regs; hmax -> dmax; reload; hmin -> dmin.
template <bool PREABS, int R, int TH>
__global__ __launch_bounds__(256, 4) void dual_pool(const float* __restrict__ src,
                                                    float* __restrict__ dmax,
                                                    float* __restrict__ dmin) {
    constexpr int TILES = HH / TH;
    constexpr int W = 2 * R + 1;
    constexpr int NS = (TH * 64) / 256;
    __shared__ float lbuf[TH * PADW];

    const int plane = blockIdx.x / TILES;
    const int tile  = blockIdx.x % TILES;
    const int i0    = tile * TH;
    const size_t pbase = (size_t)plane * SS;
    const float* sp = src + pbase;
    const int t = threadIdx.x;
    const int ca = swz(2 * t);                     // ca+1 == swz(2t+1)

    float2 rb[W];
    float2 keepmn[TH];
    auto ld = [&](int gi) -> float2 {
        float2 u = ((const float2*)(sp + (size_t)gi * WW))[t];
        if (PREABS) { u.x = fabsf(u.x); u.y = fabsf(u.y); }
        return u;
    };
    #pragma unroll
    for (int k = 0; k < W; ++k)
        if ((unsigned)(i0 - R + k) < (unsigned)HH) rb[k] = ld(i0 - R + k);
    #pragma unroll
    for (int oi = 0; oi < TH; ++oi) {
        if (oi > 0) {
            if ((unsigned)(i0 + oi + R) < (unsigned)HH) rb[(oi - 1) % W] = ld(i0 + oi + R);
        }
        float2 mx = make_float2(-FINF, -FINF), mn = make_float2(FINF, FINF);
        #pragma unroll
        for (int k = 0; k < W; ++k) {
            int wrap = (oi > k) ? ((oi - 1 - k) / W + 1) : 0;   // compile-time
            int ro = k - R + wrap * W;                          // exact row in slot k
            if ((unsigned)(i0 + ro) < (unsigned)HH) {           // block-uniform branch
                mx.x = fmaxf(mx.x, rb[k].x); mx.y = fmaxf(mx.y, rb[k].y);
                mn.x = fminf(mn.x, rb[k].x); mn.y = fminf(mn.y, rb[k].y);
            }
        }
        lbuf[oi * PADW + ca] = mx.x; lbuf[oi * PADW + ca + 1] = mx.y;
        keepmn[oi] = mn;
    }
    __syncthreads();

    // horizontal max -> dmax
    #pragma unroll
    for (int si = 0; si < NS; ++si) {
        int s = si * 256 + t;
        int rr = s >> 6, j0 = (s & 63) << 3;
        const float* rx = &lbuf[rr * PADW];
        float vx[2 * R + 8];
        #pragma unroll
        for (int k = 0; k < 2 * R + 8; ++k) {
            int jj = j0 - R + k;
            bool ok = (unsigned)jj < (unsigned)WW;
            int jc = swz(min(max(jj, 0), WW - 1));
            vx[k] = ok ? rx[jc] : -FINF;
        }
        float ox[8];
        #pragma unroll
        for (int d = 0; d < 8; ++d) {
            float mx = vx[d];
            #pragma unroll
            for (int k = 1; k <= 2 * R; ++k) mx = fmaxf(mx, vx[d + k]);
            ox[d] = mx;
        }
        size_t o = pbase + (size_t)(i0 + rr) * WW + j0;
        ((float4*)&dmax[o])[0] = make_float4(ox[0], ox[1], ox[2], ox[3]);
        ((float4*)&dmax[o])[1] = make_float4(ox[4], ox[5], ox[6], ox[7]);
    }
    __syncthreads();

    // swap in the vertical-min column results
    #pragma unroll
    for (int oi = 0; oi < TH; ++oi) {
        lbuf[oi * PADW + ca] = keepmn[oi].x;
        lbuf[oi * PADW + ca + 1] = keepmn[oi].y;
    }
    __syncthreads();

    // horizontal min -> dmin
    #pragma unroll
    for (int si = 0; si < NS; ++si) {
        int s = si * 256 + t;
        int rr = s >> 6, j0 = (s & 63) << 3;
        const float* rn = &lbuf[rr * PADW];
        float vn[2 * R + 8];
        #pragma unroll
        for (int k = 0; k < 2 * R + 8; ++k) {
            int jj = j0 - R + k;
            bool ok = (unsigned)jj < (unsigned)WW;
            int jc = swz(min(max(jj, 0), WW - 1));
            vn[k] = ok ? rn[jc] : FINF;
        }
        float on[8];
        #pragma unroll
        for (int d = 0; d < 8; ++d) {
            float mn = vn[d];
            #pragma unroll
            for (int k = 1; k <= 2 * R; ++k) mn = fminf(mn, vn[d + k]);
            on[d] = mn;
        }
        size_t o = pbase + (size_t)(i0 + rr) * WW + j0;
        ((float4*)&dmin[o])[0] = make_float4(on[0], on[1], on[2], on[3]);
        ((float4*)&dmin[o])[1] = make_float4(on[4], on[5], on[6], on[7]);
    }
}

// ---------------- single avg pool (abs output), division-free ----------------
template <int R, int TH>
__global__ __launch_bounds__(256, 4) void avg_abs_pool(const float* __restrict__ src,
                                                       float* __restrict__ dst) {
    constexpr int TILES = HH / TH;
    __shared__ float ls[TH * PADW];
    const int plane = blockIdx.x / TILES;
    const int tile  = blockIdx.x % TILES;
    const int i0    = tile * TH;
    const size_t pbase = (size_t)plane * SS;
    const float* sp = src + pbase;
    const int t = threadIdx.x;

    auto ld = [&](int gi) -> float2 {
        if ((unsigned)gi < (unsigned)HH) return ((const float2*)(sp + (size_t)gi * WW))[t];
        return make_float2(0.f, 0.f);
    };
    float2 acc = make_float2(0.f, 0.f);
    #pragma unroll
    for (int k = -R; k <= R; ++k) { float2 v = ld(i0 + k); acc.x += v.x; acc.y += v.y; }
    const int ca = swz(2 * t);
    ls[ca] = acc.x; ls[ca + 1] = acc.y;
    #pragma unroll
    for (int oi = 1; oi < TH; ++oi) {
        float2 a = ld(i0 + oi + R), s = ld(i0 + oi - R - 1);
        acc.x += a.x - s.x; acc.y += a.y - s.y;
        ls[oi * PADW + ca] = acc.x; ls[oi * PADW + ca + 1] = acc.y;
    }
    __syncthreads();

    for (int s = t; s < TH * 64; s += 256) {
        int rr = s >> 6, j0 = (s & 63) << 3;
        int i = i0 + rr;
        int ch = min(i + R, HH - 1) - max(i - R, 0) + 1;
        float invch = invsmall<R>(ch);
        const float* row = &ls[rr * PADW];
        int lo = max(j0 - R, 0), hi = min(j0 + R, WW - 1);
        float racc = 0.f;
        for (int jj = lo; jj <= hi; ++jj) racc += row[swz(jj)];
        float ov[8];
        #pragma unroll
        for (int d = 0; d < 8; ++d) {
            if (d > 0) {
                int add = j0 + d + R, sub = j0 + d - R - 1;
                if (add < WW) racc += row[swz(add)];
                if (sub >= 0) racc -= row[swz(sub)];
            }
            int j = j0 + d;
            int cw = min(j + R, WW - 1) - max(j - R, 0) + 1;
            ov[d] = fabsf(racc * (invch * invsmall<R>(cw)));
        }
        float4* d4 = (float4*)&dst[pbase + (size_t)i * WW + j0];
        d4[0] = make_float4(ov[0], ov[1], ov[2], ov[3]);
        d4[1] = make_float4(ov[4], ov[5], ov[6], ov[7]);
    }
}

// ---------------- fused gn1: dual-stream avg17 + epilogue, SINGLE pass ----------------
// out = (|e1|*chcw - racc2)/(|racc1 - racc2| + 1e-4*chcw)
// Source-split vertical: threads 0-127 own 4 cols of s1 (float4 loads, 16B/lane),
// threads 128-255 own 4 cols of s2. Dual-half LDS rows [s1:576|s2:576] with the
// proven swz (j>>3) skew; float4 LDS writes stay within a skew group (4-aligned
// never crosses the 8-boundary). NO per-thread arrays. 8-row window: 36864 B
// -> 4 blocks/CU.
template <int R, int TH, int SUB>
__global__ __launch_bounds__(256, 4) void gn1_fused(const float* __restrict__ s1,
                                                    const float* __restrict__ s2,
                                                    const float* __restrict__ e1,
                                                    float* __restrict__ dst) {
    constexpr int TILES = HH / TH;
    constexpr int NSP = TH / SUB;
    constexpr int NSH = (SUB * 64) / 256;
    __shared__ float lbuf[SUB * DPW];              // 8*1152*4 = 36864 B
    const int plane = blockIdx.x / TILES;
    const int tile  = blockIdx.x % TILES;
    const int i0    = tile * TH;
    const size_t pbase = (size_t)plane * SS;
    const int t = threadIdx.x;
    const int tc = t & 127;                        // 4-column group
    const int cbase = (t >= 128) ? PADW : 0;       // s1 half / s2 half
    const float* sp = ((t >= 128) ? s2 : s1) + pbase;
    const int ca = swz(4 * tc);                    // float4-safe (4-aligned group)

    auto ld = [&](int gi) -> float4 {
        if ((unsigned)gi < (unsigned)HH) return ((const float4*)(sp + (size_t)gi * WW))[tc];
        return make_float4(0.f, 0.f, 0.f, 0.f);
    };
    float4 a = make_float4(0.f, 0.f, 0.f, 0.f);
    #pragma unroll
    for (int k = -R; k <= R; ++k) {
        float4 v = ld(i0 + k);
        a.x += v.x; a.y += v.y; a.z += v.z; a.w += v.w;
    }

    #pragma unroll
    for (int p = 0; p < NSP; ++p) {
        if (p > 0) __syncthreads();                // window free (prev horizontal done)
        #pragma unroll
        for (int q = 0; q < SUB; ++q) {
            const int oi = p * SUB + q;
            if (oi > 0) {
                float4 u = ld(i0 + oi + R), s = ld(i0 + oi - R - 1);
                a.x += u.x - s.x; a.y += u.y - s.y;
                a.z += u.z - s.z; a.w += u.w - s.w;
            }
            *(float4*)&lbuf[q * DPW + cbase + ca] = a;
        }
        __syncthreads();

        #pragma unroll
        for (int si = 0; si < NSH; ++si) {
            int s = si * 256 + t;
            int rr = s >> 6, j0 = (s & 63) << 3;
            int i = i0 + p * SUB + rr;
            int ch = min(i + R, HH - 1) - max(i - R, 0) + 1;
            const float* rowA = &lbuf[rr * DPW];
            const float* rowB = rowA + PADW;
            size_t rowbase = pbase + (size_t)i * WW + j0;

            float e1v[8];
            {
                float4 q0 = ((const float4*)(e1 + rowbase))[0];
                float4 q1 = ((const float4*)(e1 + rowbase))[1];
                e1v[0]=q0.x; e1v[1]=q0.y; e1v[2]=q0.z; e1v[3]=q0.w;
                e1v[4]=q1.x; e1v[5]=q1.y; e1v[6]=q1.z; e1v[7]=q1.w;
            }

            int lo = max(j0 - R, 0), hi = min(j0 + R, WW - 1);
            float r1 = 0.f, r2 = 0.f;
            for (int jj = lo; jj <= hi; ++jj) {
                int jc = swz(jj);
                r1 += rowA[jc]; r2 += rowB[jc];
            }
            float ov[8];
            #pragma unroll
            for (int d = 0; d < 8; ++d) {
                if (d > 0) {
                    int add = j0 + d + R, sub = j0 + d - R - 1;
                    if (add < WW) { int jc = swz(add); r1 += rowA[jc]; r2 += rowB[jc]; }
                    if (sub >= 0) { int jc = swz(sub); r1 -= rowA[jc]; r2 -= rowB[jc]; }
                }
                int j = j0 + d;
                int cw = min(j + R, WW - 1) - max(j - R, 0) + 1;
                float chcw = (float)(ch * cw);
                float den = fabsf(r1 - r2) + 1e-4f * chcw;
                ov[d] = (fabsf(e1v[d]) * chcw - r2) / den;
            }
            float4* d4 = (float4*)&dst[rowbase];
            d4[0] = make_float4(ov[0], ov[1], ov[2], ov[3]);
            d4[1] = make_float4(ov[4], ov[5], ov[6], ov[7]);
        }
    }
}

// ---------------- fused final: dual-stream avg7 + map + paired reduction ----------------
// 512 threads: lower half = plane R, upper half = plane L (=R+16). Within each
// half, threads 0-127 stream s1 (float4), 128-255 stream s2. No per-thread
// arrays. Per slice: L-half posts exp(-10*mapL) via exch, R-half accumulates
// mapR*exp(-10*mapR)*exch. LDS = 2*8*1152*4 + 8192 = 81920 B -> 2 blocks/CU.
template <int R, int TH, int SUB>
__global__ __launch_bounds__(512, 4) void final_fused(const float* __restrict__ s1,
                                                      const float* __restrict__ s2,
                                                      const float* __restrict__ e1,
                                                      const float* __restrict__ e2,
                                                      float* __restrict__ out, float scale) {
    constexpr int TILES = HH / TH;
    constexpr int NSP = TH / SUB;
    constexpr int NSH = (SUB * 64) / 256;
    __shared__ float lbuf[2 * SUB * DPW];          // 73728 B
    __shared__ float exch[2048];                   // 8192 B (also final reduction)

    const int t    = threadIdx.x;
    const int half = t >> 8;                       // 0 = R-plane, 1 = L-plane
    const int tl   = t & 255;
    const int tc   = tl & 127;                     // 4-column group
    const int cbase = (tl >= 128) ? PADW : 0;      // s1 half / s2 half
    const int pairidx = blockIdx.x / TILES;
    const int tile    = blockIdx.x % TILES;
    const int i0      = tile * TH;
    const int planeR  = pairidx + ((pairidx >> 4) << 4);   // 0..15->0..15; 16..31->32..47
    const size_t pbase = (size_t)(planeR + half * 16) * SS;
    const float* sp = ((tl >= 128) ? s2 : s1) + pbase;
    float* myl = lbuf + half * (SUB * DPW);
    const int ca = swz(4 * tc);

    auto ld = [&](int gi) -> float4 {
        if ((unsigned)gi < (unsigned)HH) return ((const float4*)(sp + (size_t)gi * WW))[tc];
        return make_float4(0.f, 0.f, 0.f, 0.f);
    };
    float4 a = make_float4(0.f, 0.f, 0.f, 0.f);
    #pragma unroll
    for (int k = -R; k <= R; ++k) {
        float4 v = ld(i0 + k);
        a.x += v.x; a.y += v.y; a.z += v.z; a.w += v.w;
    }

    float acc = 0.f;
    #pragma unroll
    for (int p = 0; p < NSP; ++p) {
        if (p > 0) __syncthreads();
        #pragma unroll
        for (int q = 0; q < SUB; ++q) {
            const int oi = p * SUB + q;
            if (oi > 0) {
                float4 u = ld(i0 + oi + R), s = ld(i0 + oi - R - 1);
                a.x += u.x - s.x; a.y += u.y - s.y;
                a.z += u.z - s.z; a.w += u.w - s.w;
            }
            *(float4*)&myl[q * DPW + cbase + ca] = a;
        }
        __syncthreads();

        #pragma unroll
        for (int si = 0; si < NSH; ++si) {
            int s = si * 256 + tl;
            int rr = s >> 6, j0 = (s & 63) << 3;
            int i = i0 + p * SUB + rr;
            int ch = min(i + R, HH - 1) - max(i - R, 0) + 1;
            const float* rowA = &myl[rr * DPW];
            const float* rowB = rowA + PADW;
            size_t rowbase = pbase + (size_t)i * WW + j0;

            float e1v[8], e2v[8];
            {
                float4 q0 = ((const float4*)(e1 + rowbase))[0];
                float4 q1 = ((const float4*)(e1 + rowbase))[1];
                e1v[0]=q0.x; e1v[1]=q0.y; e1v[2]=q0.z; e1v[3]=q0.w;
                e1v[4]=q1.x; e1v[5]=q1.y; e1v[6]=q1.z; e1v[7]=q1.w;
                float4 b0 = ((const float4*)(e2 + rowbase))[0];
                float4 b1 = ((const float4*)(e2 + rowbase))[1];
                e2v[0]=b0.x; e2v[1]=b0.y; e2v[2]=b0.z; e2v[3]=b0.w;
                e2v[4]=b1.x; e2v[5]=b1.y; e2v[6]=b1.z; e2v[7]=b1.w;
            }

            int lo = max(j0 - R, 0), hi = min(j0 + R, WW - 1);
            float r1 = 0.f, r2 = 0.f;
            for (int jj = lo; jj <= hi; ++jj) {
                int jc = swz(jj);
                r1 += rowA[jc]; r2 += rowB[jc];
            }
            float mp[8];
            #pragma unroll
            for (int d = 0; d < 8; ++d) {
                if (d > 0) {
                    int add = j0 + d + R, sub = j0 + d - R - 1;
                    if (add < WW) { int jc = swz(add); r1 += rowA[jc]; r2 += rowB[jc]; }
                    if (sub >= 0) { int jc = swz(sub); r1 -= rowA[jc]; r2 -= rowB[jc]; }
                }
                int j = j0 + d;
                int cw = min(j + R, WW - 1) - max(j - R, 0) + 1;
                float chcw = (float)(ch * cw);
                float den = fabsf(r1 - r2) + 1e-4f * chcw;
                mp[d] = ((e1v[d] * chcw - r2) / den + 0.01f) * e2v[d];
            }
            if (half == 1) {                       // wave-uniform
                #pragma unroll
                for (int d = 0; d < 8; ++d) exch[d * 256 + tl] = expf(-10.f * mp[d]);
            }
            __syncthreads();
            if (half == 0) {
                #pragma unroll
                for (int d = 0; d < 8; ++d)
                    acc += mp[d] * expf(-10.f * mp[d]) * exch[d * 256 + tl];
            }
            __syncthreads();                       // exch free for next slice
        }
    }

    // block reduction (upper half contributes 0)
    #pragma unroll
    for (int off = 32; off; off >>= 1) acc += __shfl_down(acc, off);
    int lane = t & 63, wv = t >> 6;                // 8 waves
    if (lane == 0) exch[wv] = acc;
    __syncthreads();
    if (t == 0) {
        float v = 0.f;
        #pragma unroll
        for (int k = 0; k < 8; ++k) v += exch[k];
        atomicAdd(out, v * scale);
    }
}

// ---------------- host orchestration ----------------
// Champion pipeline; gn1_fused/final_fused get swz skew + float4 source-split.
// G=g -> dual9(G->A,B) -> gn1_fused(A,B,G->C=gn1) -> avg_abs(G->A=go)
// -> dual7(A->B=max7, G=min7) -> final_fused(B,G,A,C -> atomicAdd out).

extern "C" void kernel_launch(void* const* d_in, const int* in_sizes, int n_in,
                              void* d_out, int out_size, void* d_ws, size_t ws_size,
                              hipStream_t stream) {
    const float* Rrgb = (const float*)d_in[0];
    const float* Lrgb = (const float*)d_in[1];
    float* out = (float*)d_out;
    float* w = (float*)d_ws;
    const float scale = 1.f / (float)P16N;
    const int gradblk = (P16N / 4 + 255) / 256;

    hipMemsetAsync(out, 0, sizeof(float) * (size_t)out_size, stream);

    const size_t stack64 = (size_t)64 * SS;
    if (ws_size >= 4 * stack64 * sizeof(float)) {
        // 4 buffers of 64 planes: layout [0..16)=Rgx [16..32)=Lgx [32..48)=Rgy [48..64)=Lgy
        float* G = w;
        float* A = G + stack64;
        float* B = A + stack64;
        float* C = B + stack64;
        grad_both<<<gradblk, 256, 0, stream>>>(Rrgb, G, 0, 32, 2);
        grad_both<<<gradblk, 256, 0, stream>>>(Lrgb, G, 16, 48, 2);
        int gp = 64 * (HH / 16);
        dual_pool<true, 4, 16><<<gp, 256, 0, stream>>>(G, A, B);          // A=max9|g|, B=min9|g|
        gn1_fused<8, 16, 8><<<gp, 256, 0, stream>>>(A, B, G, C);          // C=gn1
        avg_abs_pool<2, 16><<<gp, 256, 0, stream>>>(G, A);                // A=go (G dead)
        dual_pool<false, 3, 16><<<gp, 256, 0, stream>>>(A, B, G);         // B=max7, G=min7
        int fp = 32 * (HH / 16);
        final_fused<3, 16, 8><<<fp, 512, 0, stream>>>(B, G, A, C, out, scale);
    } else {
        // fallback: 4 buffers of 32 planes (128 MiB), one direction at a time
        const size_t stack32 = (size_t)32 * SS;
        float* G = w;
        float* A = G + stack32;
        float* B = A + stack32;
        float* C = B + stack32;
        for (int dir = 0; dir < 2; ++dir) {
            grad_both<<<gradblk, 256, 0, stream>>>(Rrgb, G, 0, 0, dir);
            grad_both<<<gradblk, 256, 0, stream>>>(Lrgb, G, 16, 16, dir);
            int gp = 32 * (HH / 16);
            dual_pool<true, 4, 16><<<gp, 256, 0, stream>>>(G, A, B);
            gn1_fused<8, 16, 8><<<gp, 256, 0, stream>>>(A, B, G, C);
            avg_abs_pool<2, 16><<<gp, 256, 0, stream>>>(G, A);
            dual_pool<false, 3, 16><<<gp, 256, 0, stream>>>(A, B, G);
            int fp = 16 * (HH / 16);
            final_fused<3, 16, 8><<<fp, 512, 0, stream>>>(B, G, A, C, out, scale);
        }
    }
}

// Round 12
// 354.416 us; speedup vs baseline: 1.0338x; 1.0338x over previous
//
#include <hip/hip_runtime.h>

#define HH 512
#define WW 512
#define SS (HH * WW)          // elements per plane (2^18)
#define P16N (16 * SS)        // 16 planes (2^22)
#define PADW 576              // skewed LDS row: addr(j) = j + (j>>3)
#define DPW (2 * PADW)        // dual-half row: [s1 : 576 | s2 : 576]

constexpr float FINF = 3.402823466e38f;

__device__ __forceinline__ int swz(int j) { return j + (j >> 3); }

__device__ __forceinline__ float gray1(float r, float g, float b) {
    return 0.299f * r + 0.587f * g + 0.114f * b;
}

// inverse of small integer c in [R+1, 2R+1] without v_div (cmp+cndmask chain)
template <int R>
__device__ __forceinline__ float invsmall(int c) {
    float r = 1.f / (float)(2 * R + 1);
    #pragma unroll
    for (int v = R + 1; v < 2 * R + 1; ++v)
        if (c == v) r = 1.f / (float)v;      // compile-time constants
    return r;
}

// ---------------- grad (gray fused, both dirs, 4 px/thread) ----------------
__global__ __launch_bounds__(256) void grad_both(const float* __restrict__ rgb,
                                                 float* __restrict__ dst,
                                                 int gxp0, int gyp0, int dirsel) {
    int sp = blockIdx.x * 256 + threadIdx.x;
    int idx = sp << 2;                             // [0, P16N)
    int img = idx >> 18;
    int pix = idx & (SS - 1);
    int i = pix >> 9, j0 = pix & (WW - 1);
    const float* p0 = rgb + (size_t)img * 3 * SS + pix;

    float4 r = *(const float4*)p0;
    float4 g = *(const float4*)(p0 + SS);
    float4 b = *(const float4*)(p0 + 2 * SS);
    float4 gy4 = make_float4(gray1(r.x, g.x, b.x), gray1(r.y, g.y, b.y),
                             gray1(r.z, g.z, b.z), gray1(r.w, g.w, b.w));
    if (dirsel != 1) {
        float grs = 0.f;
        if (j0 + 4 < WW) grs = gray1(p0[4], p0[SS + 4], p0[2 * SS + 4]);
        float4 gx = make_float4(gy4.x - gy4.y, gy4.y - gy4.z, gy4.z - gy4.w, gy4.w - grs);
        *(float4*)(dst + (size_t)(gxp0 + img) * SS + pix) = gx;
    }
    if (dirsel != 0) {
        float4 gd = make_float4(0.f, 0.f, 0.f, 0.f);
        if (i < HH - 1) {
            float4 r2 = *(const float4*)(p0 + WW);
            float4 g2 = *(const float4*)(p0 + SS + WW);
            float4 b2 = *(const float4*)(p0 + 2 * SS + WW);
            gd = make_float4(gray1(r2.x, g2.x, b2.x), gray1(r2.y, g2.y, b2.y),
                             gray1(r2.z, g2.z, b2.z), gray1(r2.w, g2.w, b2.w));
        }
        float4 gy = make_float4(gy4.x - gd.x, gy4.y - gd.y, gy4.z - gd.z, gy4.w - gd.w);
        *(float4*)(dst + (size_t)(gyp0 + img) * SS + pix) = gy;
    }
}

// ---------------- dual max+min pool, SUB-PHASED ----------------
// TH=16 tile (unchanged traffic) streamed through a SUB-row LDS window
// (SUB=8 -> 18432 B -> up to 8 blocks/CU). Cross-phase state: ring rb[W]
// (regs) + keepmn[SUB] (static-indexed) — the no-spill profile. Exact
// wrap-counted validity mask (compile-time except i0).
template <bool PREABS, int R, int TH, int SUB>
__global__ __launch_bounds__(256, 4) void dual_pool(const float* __restrict__ src,
                                                    float* __restrict__ dmax,
                                                    float* __restrict__ dmin) {
    constexpr int TILES = HH / TH;
    constexpr int W = 2 * R + 1;
    constexpr int NSP = TH / SUB;
    constexpr int NSH = (SUB * 64) / 256;
    __shared__ float lbuf[SUB * PADW];

    const int plane = blockIdx.x / TILES;
    const int tile  = blockIdx.x % TILES;
    const int i0    = tile * TH;
    const size_t pbase = (size_t)plane * SS;
    const float* sp = src + pbase;
    const int t = threadIdx.x;
    const int ca = swz(2 * t);                     // ca+1 == swz(2t+1)

    float2 rb[W];
    float2 keepmn[SUB];
    auto ld = [&](int gi) -> float2 {
        float2 u = ((const float2*)(sp + (size_t)gi * WW))[t];
        if (PREABS) { u.x = fabsf(u.x); u.y = fabsf(u.y); }
        return u;
    };
    #pragma unroll
    for (int k = 0; k < W; ++k)
        if ((unsigned)(i0 - R + k) < (unsigned)HH) rb[k] = ld(i0 - R + k);

    #pragma unroll
    for (int p = 0; p < NSP; ++p) {
        if (p > 0) __syncthreads();                // lbuf free (prev hmin done)
        // vertical: rows p*SUB .. p*SUB+SUB-1 (max -> LDS, min -> regs)
        #pragma unroll
        for (int q = 0; q < SUB; ++q) {
            const int oi = p * SUB + q;            // compile-time
            if (oi > 0) {
                if ((unsigned)(i0 + oi + R) < (unsigned)HH) rb[(oi - 1) % W] = ld(i0 + oi + R);
            }
            float2 mx = make_float2(-FINF, -FINF), mn = make_float2(FINF, FINF);
            #pragma unroll
            for (int k = 0; k < W; ++k) {
                int wrap = (oi > k) ? ((oi - 1 - k) / W + 1) : 0;   // compile-time
                int ro = k - R + wrap * W;                          // exact row in slot k
                if ((unsigned)(i0 + ro) < (unsigned)HH) {           // block-uniform
                    mx.x = fmaxf(mx.x, rb[k].x); mx.y = fmaxf(mx.y, rb[k].y);
                    mn.x = fminf(mn.x, rb[k].x); mn.y = fminf(mn.y, rb[k].y);
                }
            }
            lbuf[q * PADW + ca] = mx.x; lbuf[q * PADW + ca + 1] = mx.y;
            keepmn[q] = mn;
        }
        __syncthreads();

        // horizontal max -> dmax
        #pragma unroll
        for (int si = 0; si < NSH; ++si) {
            int s = si * 256 + t;
            int rr = s >> 6, j0 = (s & 63) << 3;
            const float* rx = &lbuf[rr * PADW];
            float vx[2 * R + 8];
            #pragma unroll
            for (int k = 0; k < 2 * R + 8; ++k) {
                int jj = j0 - R + k;
                bool ok = (unsigned)jj < (unsigned)WW;
                int jc = swz(min(max(jj, 0), WW - 1));
                vx[k] = ok ? rx[jc] : -FINF;
            }
            float ox[8];
            #pragma unroll
            for (int d = 0; d < 8; ++d) {
                float mx = vx[d];
                #pragma unroll
                for (int k = 1; k <= 2 * R; ++k) mx = fmaxf(mx, vx[d + k]);
                ox[d] = mx;
            }
            size_t o = pbase + (size_t)(i0 + p * SUB + rr) * WW + j0;
            ((float4*)&dmax[o])[0] = make_float4(ox[0], ox[1], ox[2], ox[3]);
            ((float4*)&dmax[o])[1] = make_float4(ox[4], ox[5], ox[6], ox[7]);
        }
        __syncthreads();

        #pragma unroll
        for (int q = 0; q < SUB; ++q) {
            lbuf[q * PADW + ca] = keepmn[q].x;
            lbuf[q * PADW + ca + 1] = keepmn[q].y;
        }
        __syncthreads();

        // horizontal min -> dmin
        #pragma unroll
        for (int si = 0; si < NSH; ++si) {
            int s = si * 256 + t;
            int rr = s >> 6, j0 = (s & 63) << 3;
            const float* rn = &lbuf[rr * PADW];
            float vn[2 * R + 8];
            #pragma unroll
            for (int k = 0; k < 2 * R + 8; ++k) {
                int jj = j0 - R + k;
                bool ok = (unsigned)jj < (unsigned)WW;
                int jc = swz(min(max(jj, 0), WW - 1));
                vn[k] = ok ? rn[jc] : FINF;
            }
            float on[8];
            #pragma unroll
            for (int d = 0; d < 8; ++d) {
                float mn = vn[d];
                #pragma unroll
                for (int k = 1; k <= 2 * R; ++k) mn = fminf(mn, vn[d + k]);
                on[d] = mn;
            }
            size_t o = pbase + (size_t)(i0 + p * SUB + rr) * WW + j0;
            ((float4*)&dmin[o])[0] = make_float4(on[0], on[1], on[2], on[3]);
            ((float4*)&dmin[o])[1] = make_float4(on[4], on[5], on[6], on[7]);
        }
    }
}

// ---------------- single avg pool (abs output), SUB-PHASED, division-free ----------------
template <int R, int TH, int SUB>
__global__ __launch_bounds__(256, 4) void avg_abs_pool(const float* __restrict__ src,
                                                       float* __restrict__ dst) {
    constexpr int TILES = HH / TH;
    constexpr int NSP = TH / SUB;
    constexpr int NSH = (SUB * 64) / 256;
    __shared__ float ls[SUB * PADW];
    const int plane = blockIdx.x / TILES;
    const int tile  = blockIdx.x % TILES;
    const int i0    = tile * TH;
    const size_t pbase = (size_t)plane * SS;
    const float* sp = src + pbase;
    const int t = threadIdx.x;
    const int ca = swz(2 * t);

    auto ld = [&](int gi) -> float2 {
        if ((unsigned)gi < (unsigned)HH) return ((const float2*)(sp + (size_t)gi * WW))[t];
        return make_float2(0.f, 0.f);
    };
    float2 acc = make_float2(0.f, 0.f);
    #pragma unroll
    for (int k = -R; k <= R; ++k) { float2 v = ld(i0 + k); acc.x += v.x; acc.y += v.y; }

    #pragma unroll
    for (int p = 0; p < NSP; ++p) {
        if (p > 0) __syncthreads();
        #pragma unroll
        for (int q = 0; q < SUB; ++q) {
            const int oi = p * SUB + q;
            if (oi > 0) {
                float2 a = ld(i0 + oi + R), s = ld(i0 + oi - R - 1);
                acc.x += a.x - s.x; acc.y += a.y - s.y;
            }
            ls[q * PADW + ca] = acc.x; ls[q * PADW + ca + 1] = acc.y;
        }
        __syncthreads();

        #pragma unroll
        for (int si = 0; si < NSH; ++si) {
            int s = si * 256 + t;
            int rr = s >> 6, j0 = (s & 63) << 3;
            int i = i0 + p * SUB + rr;
            int ch = min(i + R, HH - 1) - max(i - R, 0) + 1;
            float invch = invsmall<R>(ch);
            const float* row = &ls[rr * PADW];
            int lo = max(j0 - R, 0), hi = min(j0 + R, WW - 1);
            float racc = 0.f;
            for (int jj = lo; jj <= hi; ++jj) racc += row[swz(jj)];
            float ov[8];
            #pragma unroll
            for (int d = 0; d < 8; ++d) {
                if (d > 0) {
                    int add = j0 + d + R, sub = j0 + d - R - 1;
                    if (add < WW) racc += row[swz(add)];
                    if (sub >= 0) racc -= row[swz(sub)];
                }
                int j = j0 + d;
                int cw = min(j + R, WW - 1) - max(j - R, 0) + 1;
                ov[d] = fabsf(racc * (invch * invsmall<R>(cw)));
            }
            float4* d4 = (float4*)&dst[pbase + (size_t)i * WW + j0];
            d4[0] = make_float4(ov[0], ov[1], ov[2], ov[3]);
            d4[1] = make_float4(ov[4], ov[5], ov[6], ov[7]);
        }
    }
}

// ---------------- fused gn1: dual-stream avg17 + epilogue, SUB=4 window ----------------
// out = (|e1|*chcw - racc2)/(|racc1 - racc2| + 1e-4*chcw)
// Source-split vertical (threads 0-127: s1 float4; 128-255: s2). Dual-half LDS
// rows [s1:576|s2:576], swz skew. No per-thread arrays. SUB=4 window:
// 4*1152*4 = 18432 B -> up to 8 blocks/CU at VGPR<=64.
template <int R, int TH, int SUB>
__global__ __launch_bounds__(256, 4) void gn1_fused(const float* __restrict__ s1,
                                                    const float* __restrict__ s2,
                                                    const float* __restrict__ e1,
                                                    float* __restrict__ dst) {
    constexpr int TILES = HH / TH;
    constexpr int NSP = TH / SUB;
    constexpr int NSH = (SUB * 64) / 256;
    __shared__ float lbuf[SUB * DPW];
    const int plane = blockIdx.x / TILES;
    const int tile  = blockIdx.x % TILES;
    const int i0    = tile * TH;
    const size_t pbase = (size_t)plane * SS;
    const int t = threadIdx.x;
    const int tc = t & 127;                        // 4-column group
    const int cbase = (t >= 128) ? PADW : 0;       // s1 half / s2 half
    const float* sp = ((t >= 128) ? s2 : s1) + pbase;
    const int ca = swz(4 * tc);                    // constant skew across the 4

    auto ld = [&](int gi) -> float4 {
        if ((unsigned)gi < (unsigned)HH) return ((const float4*)(sp + (size_t)gi * WW))[tc];
        return make_float4(0.f, 0.f, 0.f, 0.f);
    };
    float4 a = make_float4(0.f, 0.f, 0.f, 0.f);
    #pragma unroll
    for (int k = -R; k <= R; ++k) {
        float4 v = ld(i0 + k);
        a.x += v.x; a.y += v.y; a.z += v.z; a.w += v.w;
    }

    #pragma unroll
    for (int p = 0; p < NSP; ++p) {
        if (p > 0) __syncthreads();                // window free (prev horizontal done)
        #pragma unroll
        for (int q = 0; q < SUB; ++q) {
            const int oi = p * SUB + q;
            if (oi > 0) {
                float4 u = ld(i0 + oi + R), s = ld(i0 + oi - R - 1);
                a.x += u.x - s.x; a.y += u.y - s.y;
                a.z += u.z - s.z; a.w += u.w - s.w;
            }
            *(float4*)&lbuf[q * DPW + cbase + ca] = a;
        }
        __syncthreads();

        #pragma unroll
        for (int si = 0; si < NSH; ++si) {
            int s = si * 256 + t;
            int rr = s >> 6, j0 = (s & 63) << 3;
            int i = i0 + p * SUB + rr;
            int ch = min(i + R, HH - 1) - max(i - R, 0) + 1;
            const float* rowA = &lbuf[rr * DPW];
            const float* rowB = rowA + PADW;
            size_t rowbase = pbase + (size_t)i * WW + j0;

            float e1v[8];
            {
                float4 q0 = ((const float4*)(e1 + rowbase))[0];
                float4 q1 = ((const float4*)(e1 + rowbase))[1];
                e1v[0]=q0.x; e1v[1]=q0.y; e1v[2]=q0.z; e1v[3]=q0.w;
                e1v[4]=q1.x; e1v[5]=q1.y; e1v[6]=q1.z; e1v[7]=q1.w;
            }

            int lo = max(j0 - R, 0), hi = min(j0 + R, WW - 1);
            float r1 = 0.f, r2 = 0.f;
            for (int jj = lo; jj <= hi; ++jj) {
                int jc = swz(jj);
                r1 += rowA[jc]; r2 += rowB[jc];
            }
            float ov[8];
            #pragma unroll
            for (int d = 0; d < 8; ++d) {
                if (d > 0) {
                    int add = j0 + d + R, sub = j0 + d - R - 1;
                    if (add < WW) { int jc = swz(add); r1 += rowA[jc]; r2 += rowB[jc]; }
                    if (sub >= 0) { int jc = swz(sub); r1 -= rowA[jc]; r2 -= rowB[jc]; }
                }
                int j = j0 + d;
                int cw = min(j + R, WW - 1) - max(j - R, 0) + 1;
                float chcw = (float)(ch * cw);
                float den = fabsf(r1 - r2) + 1e-4f * chcw;
                ov[d] = (fabsf(e1v[d]) * chcw - r2) / den;
            }
            float4* d4 = (float4*)&dst[rowbase];
            d4[0] = make_float4(ov[0], ov[1], ov[2], ov[3]);
            d4[1] = make_float4(ov[4], ov[5], ov[6], ov[7]);
        }
    }
}

// ---------------- fused final: dual-stream avg7 + map + paired reduction ----------------
// 512 threads: lower half = plane R, upper half = plane L (=R+16). Within each
// half, threads 0-127 stream s1 (float4), 128-255 stream s2. SUB=4 window:
// LDS = 2*4*1152*4 + 8192 = 45056 B -> 3 blocks/CU (24 waves).
template <int R, int TH, int SUB>
__global__ __launch_bounds__(512, 4) void final_fused(const float* __restrict__ s1,
                                                      const float* __restrict__ s2,
                                                      const float* __restrict__ e1,
                                                      const float* __restrict__ e2,
                                                      float* __restrict__ out, float scale) {
    constexpr int TILES = HH / TH;
    constexpr int NSP = TH / SUB;
    constexpr int NSH = (SUB * 64) / 256;
    __shared__ float lbuf[2 * SUB * DPW];          // 36864 B
    __shared__ float exch[2048];                   // 8192 B (also final reduction)

    const int t    = threadIdx.x;
    const int half = t >> 8;                       // 0 = R-plane, 1 = L-plane
    const int tl   = t & 255;
    const int tc   = tl & 127;                     // 4-column group
    const int cbase = (tl >= 128) ? PADW : 0;      // s1 half / s2 half
    const int pairidx = blockIdx.x / TILES;
    const int tile    = blockIdx.x % TILES;
    const int i0      = tile * TH;
    const int planeR  = pairidx + ((pairidx >> 4) << 4);   // 0..15->0..15; 16..31->32..47
    const size_t pbase = (size_t)(planeR + half * 16) * SS;
    const float* sp = ((tl >= 128) ? s2 : s1) + pbase;
    float* myl = lbuf + half * (SUB * DPW);
    const int ca = swz(4 * tc);

    auto ld = [&](int gi) -> float4 {
        if ((unsigned)gi < (unsigned)HH) return ((const float4*)(sp + (size_t)gi * WW))[tc];
        return make_float4(0.f, 0.f, 0.f, 0.f);
    };
    float4 a = make_float4(0.f, 0.f, 0.f, 0.f);
    #pragma unroll
    for (int k = -R; k <= R; ++k) {
        float4 v = ld(i0 + k);
        a.x += v.x; a.y += v.y; a.z += v.z; a.w += v.w;
    }

    float acc = 0.f;
    #pragma unroll
    for (int p = 0; p < NSP; ++p) {
        if (p > 0) __syncthreads();
        #pragma unroll
        for (int q = 0; q < SUB; ++q) {
            const int oi = p * SUB + q;
            if (oi > 0) {
                float4 u = ld(i0 + oi + R), s = ld(i0 + oi - R - 1);
                a.x += u.x - s.x; a.y += u.y - s.y;
                a.z += u.z - s.z; a.w += u.w - s.w;
            }
            *(float4*)&myl[q * DPW + cbase + ca] = a;
        }
        __syncthreads();

        #pragma unroll
        for (int si = 0; si < NSH; ++si) {
            int s = si * 256 + tl;
            int rr = s >> 6, j0 = (s & 63) << 3;
            int i = i0 + p * SUB + rr;
            int ch = min(i + R, HH - 1) - max(i - R, 0) + 1;
            const float* rowA = &myl[rr * DPW];
            const float* rowB = rowA + PADW;
            size_t rowbase = pbase + (size_t)i * WW + j0;

            float e1v[8], e2v[8];
            {
                float4 q0 = ((const float4*)(e1 + rowbase))[0];
                float4 q1 = ((const float4*)(e1 + rowbase))[1];
                e1v[0]=q0.x; e1v[1]=q0.y; e1v[2]=q0.z; e1v[3]=q0.w;
                e1v[4]=q1.x; e1v[5]=q1.y; e1v[6]=q1.z; e1v[7]=q1.w;
                float4 b0 = ((const float4*)(e2 + rowbase))[0];
                float4 b1 = ((const float4*)(e2 + rowbase))[1];
                e2v[0]=b0.x; e2v[1]=b0.y; e2v[2]=b0.z; e2v[3]=b0.w;
                e2v[4]=b1.x; e2v[5]=b1.y; e2v[6]=b1.z; e2v[7]=b1.w;
            }

            int lo = max(j0 - R, 0), hi = min(j0 + R, WW - 1);
            float r1 = 0.f, r2 = 0.f;
            for (int jj = lo; jj <= hi; ++jj) {
                int jc = swz(jj);
                r1 += rowA[jc]; r2 += rowB[jc];
            }
            float mp[8];
            #pragma unroll
            for (int d = 0; d < 8; ++d) {
                if (d > 0) {
                    int add = j0 + d + R, sub = j0 + d - R - 1;
                    if (add < WW) { int jc = swz(add); r1 += rowA[jc]; r2 += rowB[jc]; }
                    if (sub >= 0) { int jc = swz(sub); r1 -= rowA[jc]; r2 -= rowB[jc]; }
                }
                int j = j0 + d;
                int cw = min(j + R, WW - 1) - max(j - R, 0) + 1;
                float chcw = (float)(ch * cw);
                float den = fabsf(r1 - r2) + 1e-4f * chcw;
                mp[d] = ((e1v[d] * chcw - r2) / den + 0.01f) * e2v[d];
            }
            if (half == 1) {                       // wave-uniform
                #pragma unroll
                for (int d = 0; d < 8; ++d) exch[d * 256 + tl] = expf(-10.f * mp[d]);
            }
            __syncthreads();
            if (half == 0) {
                #pragma unroll
                for (int d = 0; d < 8; ++d)
                    acc += mp[d] * expf(-10.f * mp[d]) * exch[d * 256 + tl];
            }
            __syncthreads();                       // exch free for next slice
        }
    }

    // block reduction (upper half contributes 0)
    #pragma unroll
    for (int off = 32; off; off >>= 1) acc += __shfl_down(acc, off);
    int lane = t & 63, wv = t >> 6;                // 8 waves
    if (lane == 0) exch[wv] = acc;
    __syncthreads();
    if (t == 0) {
        float v = 0.f;
        #pragma unroll
        for (int k = 0; k < 8; ++k) v += exch[k];
        atomicAdd(out, v * scale);
    }
}

// ---------------- host orchestration ----------------
// Champion pipeline; all tile kernels sub-phased for occupancy at fixed
// TH=16 traffic. G=g -> dual9(G->A,B) -> gn1_fused(A,B,G->C=gn1)
// -> avg_abs(G->A=go) -> dual7(A->B=max7, G=min7)
// -> final_fused(B,G,A,C -> atomicAdd out).

extern "C" void kernel_launch(void* const* d_in, const int* in_sizes, int n_in,
                              void* d_out, int out_size, void* d_ws, size_t ws_size,
                              hipStream_t stream) {
    const float* Rrgb = (const float*)d_in[0];
    const float* Lrgb = (const float*)d_in[1];
    float* out = (float*)d_out;
    float* w = (float*)d_ws;
    const float scale = 1.f / (float)P16N;
    const int gradblk = (P16N / 4 + 255) / 256;

    hipMemsetAsync(out, 0, sizeof(float) * (size_t)out_size, stream);

    const size_t stack64 = (size_t)64 * SS;
    if (ws_size >= 4 * stack64 * sizeof(float)) {
        // 4 buffers of 64 planes: layout [0..16)=Rgx [16..32)=Lgx [32..48)=Rgy [48..64)=Lgy
        float* G = w;
        float* A = G + stack64;
        float* B = A + stack64;
        float* C = B + stack64;
        grad_both<<<gradblk, 256, 0, stream>>>(Rrgb, G, 0, 32, 2);
        grad_both<<<gradblk, 256, 0, stream>>>(Lrgb, G, 16, 48, 2);
        int gp = 64 * (HH / 16);
        dual_pool<true, 4, 16, 8><<<gp, 256, 0, stream>>>(G, A, B);       // A=max9|g|, B=min9|g|
        gn1_fused<8, 16, 4><<<gp, 256, 0, stream>>>(A, B, G, C);          // C=gn1
        avg_abs_pool<2, 16, 8><<<gp, 256, 0, stream>>>(G, A);             // A=go (G dead)
        dual_pool<false, 3, 16, 8><<<gp, 256, 0, stream>>>(A, B, G);      // B=max7, G=min7
        int fp = 32 * (HH / 16);
        final_fused<3, 16, 4><<<fp, 512, 0, stream>>>(B, G, A, C, out, scale);
    } else {
        // fallback: 4 buffers of 32 planes (128 MiB), one direction at a time
        const size_t stack32 = (size_t)32 * SS;
        float* G = w;
        float* A = G + stack32;
        float* B = A + stack32;
        float* C = B + stack32;
        for (int dir = 0; dir < 2; ++dir) {
            grad_both<<<gradblk, 256, 0, stream>>>(Rrgb, G, 0, 0, dir);
            grad_both<<<gradblk, 256, 0, stream>>>(Lrgb, G, 16, 16, dir);
            int gp = 32 * (HH / 16);
            dual_pool<true, 4, 16, 8><<<gp, 256, 0, stream>>>(G, A, B);
            gn1_fused<8, 16, 4><<<gp, 256, 0, stream>>>(A, B, G, C);
            avg_abs_pool<2, 16, 8><<<gp, 256, 0, stream>>>(G, A);
            dual_pool<false, 3, 16, 8><<<gp, 256, 0, stream>>>(A, B, G);
            int fp = 16 * (HH / 16);
            final_fused<3, 16, 4><<<fp, 512, 0, stream>>>(B, G, A, C, out, scale);
        }
    }
}